// Round 1
// baseline (174.517 us; speedup 1.0000x reference)
//
#include <hip/hip_runtime.h>
#include <math.h>

#define DIMN (1 << 20)   // 2^20 per batch row
// Layout of d_out: [2][16][DIMN] float32 (real block then imag block).

__device__ __forceinline__ void bf(float& a, float& b) { float s = a + b; b = a - b; a = s; }

__device__ __forceinline__ void bf4(float4& a, float4& b) {
    bf(a.x, b.x); bf(a.y, b.y); bf(a.z, b.z); bf(a.w, b.w);
}

// WHT over 10 bits; 16 values/lane as 4 float4.
// element index = r*256 + lane*4 + s  (s = float4 slot)
__device__ __forceinline__ void wht10_f4(float4 v[4], int lane) {
    #pragma unroll
    for (int r = 0; r < 4; r++) {
        bf(v[r].x, v[r].y); bf(v[r].z, v[r].w);   // bit0
        bf(v[r].x, v[r].z); bf(v[r].y, v[r].w);   // bit1
    }
    #pragma unroll
    for (int m = 1; m <= 32; m <<= 1) {           // bits 2..7 (lane bits)
        float sgn = (lane & m) ? -1.0f : 1.0f;
        #pragma unroll
        for (int r = 0; r < 4; r++) {
            float px = __shfl_xor(v[r].x, m);
            float py = __shfl_xor(v[r].y, m);
            float pz = __shfl_xor(v[r].z, m);
            float pw = __shfl_xor(v[r].w, m);
            v[r].x = fmaf(sgn, v[r].x, px);
            v[r].y = fmaf(sgn, v[r].y, py);
            v[r].z = fmaf(sgn, v[r].z, pz);
            v[r].w = fmaf(sgn, v[r].w, pw);
        }
    }
    bf4(v[0], v[1]); bf4(v[2], v[3]);             // bit8
    bf4(v[0], v[2]); bf4(v[1], v[3]);             // bit9
}

// WHT over 10 bits; 16 scalars/lane. element h = r*64 + lane
__device__ __forceinline__ void wht10_s(float v[16], int lane) {
    #pragma unroll
    for (int m = 1; m <= 32; m <<= 1) {           // h bits 0..5
        float sgn = (lane & m) ? -1.0f : 1.0f;
        #pragma unroll
        for (int r = 0; r < 16; r++) {
            float p = __shfl_xor(v[r], m);
            v[r] = fmaf(sgn, v[r], p);
        }
    }
    #pragma unroll
    for (int s = 1; s < 16; s <<= 1) {            // h bits 6..9
        #pragma unroll
        for (int r = 0; r < 16; r++) {
            if (!(r & s)) bf(v[r], v[r ^ s]);
        }
    }
}

// Pass 1 / Pass 3: WHT over low 10 bits of each contiguous 1024-float row.
// 32768 row-tasks viewed as [2][16][1024 rowblocks]; each wave does 4 rows.
__global__ __launch_bounds__(256) void pass13_kernel(const float* __restrict__ srcA,
                                                     const float* __restrict__ srcB,
                                                     float* __restrict__ dst) {
    const int tid  = threadIdx.x;
    const int lane = tid & 63;
    const int w    = tid >> 6;
    const int rt0  = blockIdx.x * 16 + w * 4;     // first row-task of this wave
    const float* src = (rt0 < 16384) ? (srcA + (size_t)rt0 * 1024)
                                     : (srcB + (size_t)(rt0 - 16384) * 1024);
    float* d = dst + (size_t)rt0 * 1024;

    float4 v[4][4];
    #pragma unroll
    for (int rr = 0; rr < 4; rr++)
        #pragma unroll
        for (int r = 0; r < 4; r++)
            v[rr][r] = *(const float4*)(src + rr * 1024 + r * 256 + lane * 4);

    #pragma unroll
    for (int rr = 0; rr < 4; rr++) {
        wht10_f4(v[rr], lane);
        #pragma unroll
        for (int r = 0; r < 4; r++) {
            float4 o;
            o.x = v[rr][r].x * 0.03125f;
            o.y = v[rr][r].y * 0.03125f;
            o.z = v[rr][r].z * 0.03125f;
            o.w = v[rr][r].w * 0.03125f;
            *(float4*)(d + rr * 1024 + r * 256 + lane * 4) = o;
        }
    }
}

// Pass 2: WHT over high 10 bits, rotation, WHT over high 10 bits again.
// In-place on d_out. Tile: 1024 h-rows x 8 columns x {re,im} = 64 KiB LDS.
__global__ __launch_bounds__(256) void pass2_kernel(float* __restrict__ out,
                                                    const float* __restrict__ tptr) {
    __shared__ __align__(16) float tile[2][1024][8];
    const int tid  = threadIdx.x;
    const int lane = tid & 63;
    const int w    = tid >> 6;

    // XCD-chunked swizzle (2048 wgs, 2048 % 8 == 0 -> bijective)
    int wg  = blockIdx.x;
    int swz = (wg & 7) * 256 + (wg >> 3);
    const int b  = swz >> 7;          // batch 0..15
    const int g  = swz & 127;         // column group 0..127
    const int c0 = g * 8;
    const float tval = tptr[0];

    float* baseR = out + (size_t)b * DIMN;
    float* baseI = out + (size_t)16 * DIMN + (size_t)b * DIMN;

    // ---- stage-in: coalesced global -> swizzled LDS ----
    float4 tmp[2][8];
    #pragma unroll
    for (int comp = 0; comp < 2; comp++) {
        const float* src = comp ? baseI : baseR;
        #pragma unroll
        for (int it = 0; it < 8; it++) {
            int f4id = it * 256 + tid;
            int h = f4id >> 1, q = f4id & 1;
            tmp[comp][it] = *(const float4*)(src + (size_t)h * 1024 + c0 + q * 4);
        }
    }
    #pragma unroll
    for (int comp = 0; comp < 2; comp++) {
        #pragma unroll
        for (int it = 0; it < 8; it++) {
            int f4id = it * 256 + tid;
            int h = f4id >> 1, q = f4id & 1;
            int e = (h >> 2) & 7;
            int elo = e & 3;
            float4 val = tmp[comp][it];
            // out[p] = val[p ^ elo]  (XOR permutation via 2 conditional swaps)
            bool s0 = (elo & 1) != 0;
            float x1 = s0 ? val.y : val.x, y1 = s0 ? val.x : val.y;
            float z1 = s0 ? val.w : val.z, w1 = s0 ? val.z : val.w;
            bool s1 = (elo & 2) != 0;
            float x2 = s1 ? z1 : x1, y2 = s1 ? w1 : y1;
            float z2 = s1 ? x1 : z1, w2 = s1 ? y1 : w1;
            int qp = q ^ (e >> 2);
            *(float4*)&tile[comp][h][qp * 4] = make_float4(x2, y2, z2, w2);
        }
    }
    __syncthreads();

    // ---- LDS -> registers (each wave owns columns {2w, 2w+1}) ----
    float vr[2][16], vi[2][16];
    #pragma unroll
    for (int r = 0; r < 16; r++) {
        int h = r * 64 + lane;
        int e = (lane >> 2) & 7;      // == (h>>2)&7 since (r*16)&7 == 0
        #pragma unroll
        for (int cc = 0; cc < 2; cc++) {
            int cp = (2 * w + cc) ^ e;
            vr[cc][r] = tile[0][h][cp];
            vi[cc][r] = tile[1][h][cp];
        }
    }

    // ---- WHT1-high, scale, rotate, WHT2-high ----
    const int pcl = __popc(lane);
    #pragma unroll
    for (int cc = 0; cc < 2; cc++) {
        wht10_s(vr[cc], lane);
        wht10_s(vi[cc], lane);
        const int cg = c0 + 2 * w + cc;          // full low-10 column index
        const int pbase = pcl + __popc(cg);
        float csk[5], snk[5];
        #pragma unroll
        for (int k = 0; k < 5; k++) {
            float ang = tval * (float)(20 - 2 * (pbase + k));
            sincosf(ang, &snk[k], &csk[k]);
        }
        #pragma unroll
        for (int r = 0; r < 16; r++) {
            const int pr = __popc(r);            // compile-time (r unrolled)
            float cv = csk[pr], sv = snk[pr];
            float xr = vr[cc][r] * 0.03125f;
            float xi = vi[cc][r] * 0.03125f;
            vr[cc][r] = fmaf(cv, xr, sv * xi);   // c*xr + s*xi
            vi[cc][r] = fmaf(cv, xi, -sv * xr);  // c*xi - s*xr
        }
        wht10_s(vr[cc], lane);
        wht10_s(vi[cc], lane);
    }

    // ---- registers -> LDS (own columns; no barrier needed before) ----
    #pragma unroll
    for (int r = 0; r < 16; r++) {
        int h = r * 64 + lane;
        int e = (lane >> 2) & 7;
        #pragma unroll
        for (int cc = 0; cc < 2; cc++) {
            int cp = (2 * w + cc) ^ e;
            tile[0][h][cp] = vr[cc][r] * 0.03125f;
            tile[1][h][cp] = vi[cc][r] * 0.03125f;
        }
    }
    __syncthreads();

    // ---- stage-out: swizzled LDS -> coalesced global ----
    #pragma unroll
    for (int comp = 0; comp < 2; comp++) {
        float* dstg = comp ? baseI : baseR;
        #pragma unroll
        for (int it = 0; it < 8; it++) {
            int f4id = it * 256 + tid;
            int h = f4id >> 1, q = f4id & 1;
            int e = (h >> 2) & 7;
            int elo = e & 3;
            int qp = q ^ (e >> 2);
            float4 sv = *(const float4*)&tile[comp][h][qp * 4];
            bool s0 = (elo & 1) != 0;
            float x1 = s0 ? sv.y : sv.x, y1 = s0 ? sv.x : sv.y;
            float z1 = s0 ? sv.w : sv.z, w1 = s0 ? sv.z : sv.w;
            bool s1 = (elo & 2) != 0;
            float x2 = s1 ? z1 : x1, y2 = s1 ? w1 : y1;
            float z2 = s1 ? x1 : z1, w2 = s1 ? y1 : w1;
            *(float4*)(dstg + (size_t)h * 1024 + c0 + q * 4) = make_float4(x2, y2, z2, w2);
        }
    }
}

extern "C" void kernel_launch(void* const* d_in, const int* in_sizes, int n_in,
                              void* d_out, int out_size, void* d_ws, size_t ws_size,
                              hipStream_t stream) {
    const float* xr = (const float*)d_in[0];
    const float* xi = (const float*)d_in[1];
    const float* t  = (const float*)d_in[2];
    float* out = (float*)d_out;

    // Pass 1: WHT over low 10 bits, d_in -> d_out (scaled by 1/32)
    pass13_kernel<<<2048, 256, 0, stream>>>(xr, xi, out);
    // Pass 2: WHT-high + rotate + WHT-high, in place on d_out
    pass2_kernel<<<2048, 256, 0, stream>>>(out, t);
    // Pass 3: WHT over low 10 bits again, in place on d_out
    pass13_kernel<<<2048, 256, 0, stream>>>(out, out + (size_t)16 * DIMN, out);
}